// Round 10
// baseline (357.593 us; speedup 1.0000x reference)
//
#include <hip/hip_runtime.h>

// Problem geometry: NEW_SHAPE = (16,16,512,64) flat-indexed as
//   idx = rc*32768 + i*64 + j   with rc = col*16+row, i in [0,512), j in [0,64)
//   weight element: (rc, i>>3, j); slice s = i&7 (MSB-first => shift = 14 - 2*s)
// Each thread handles 4 CONSECUTIVE elements => 16B loads/stores everywhere.
#define NELEM  (16 * 16 * 512 * 64)   // 8,388,608
#define NTHREADS_TOTAL (NELEM / 4)    // 2,097,152

typedef float f32x4 __attribute__((ext_vector_type(4)));
typedef unsigned int u32x4 __attribute__((ext_vector_type(4)));

// branchless select of one lane of an f32x4 by code c in {0,1,2,3}
__device__ __forceinline__ float sel4(f32x4 v, int c) {
    return (c & 1) ? ((c & 2) ? v.w : v.y)
                   : ((c & 2) ? v.z : v.x);
}

__global__ __launch_bounds__(256) void w2g_main_kernel(
    const f32x4*  __restrict__ input4,    // (16,16,64,64) fp32 as float4, 4 MB (L2/L3-resident)
    const f32x4*  __restrict__ meanG,     // (NELEM,4) fp32, single-use stream
    const f32x4*  __restrict__ sigG,      // (NELEM,4) fp32, single-use stream
    const f32x4*  __restrict__ eps4,      // (NELEM) fp32 as float4
    const unsigned int* __restrict__ mask8w,  // byte mask viewed as u32
    const u32x4*  __restrict__ maskw4,        // word mask viewed as uint4
    f32x4* __restrict__ out4)             // 4*NELEM: [Gp*am][Gn*am][Gp*!am][Gn*!am]
{
    int tid  = blockIdx.x * blockDim.x + threadIdx.x;   // [0, NELEM/4)
    int base = tid << 2;                                // first element index

    // ---- inline mask-dtype detection (wave-uniform, first 64 words) -------
    // byte-bool mask -> some word > 1 and none == 0x3F800000; int32/float32
    // masks both reduce to (word != 0), so only byte-vs-word matters.
    unsigned int probe = mask8w[threadIdx.x & 63];
    bool isF = (probe == 0x3F800000u);
    bool isB = (probe > 1u) && !isF;
    unsigned long long anyF = __ballot(isF);
    unsigned long long anyB = __ballot(isB);
    bool byteMode = (anyF == 0ull) && (anyB != 0ull);

    // ---- shared index decomposition (j4..j4+3 stay in one weight row) -----
    int j4    = base & 63;
    int i     = (base >> 6) & 511;
    int rc    = base >> 15;
    int shift = 14 - 2 * (i & 7);          // MSB-first 2-bit slice
    // weight float4 index: ((rc<<12) | ((i>>3)<<6) | j4) / 4
    int widx  = (rc << 10) | ((i >> 3) << 4) | (j4 >> 2);

    // ---- loads (all to distinct regs; ~11 outstanding) --------------------
    f32x4 m4[4], s4[4];
#pragma unroll
    for (int k = 0; k < 4; ++k) {
        m4[k] = __builtin_nontemporal_load(&meanG[base + k]);
        s4[k] = __builtin_nontemporal_load(&sigG[base + k]);
    }
    f32x4 ev = __builtin_nontemporal_load(&eps4[tid]);
    f32x4 wv = input4[widx];

    unsigned int mb[4];
    if (byteMode) {
        unsigned int mword = mask8w[tid];          // 4 mask bytes, aligned
        mb[0] = mword & 0xFFu;
        mb[1] = (mword >> 8)  & 0xFFu;
        mb[2] = (mword >> 16) & 0xFFu;
        mb[3] = (mword >> 24) & 0xFFu;
    } else {
        u32x4 mvec = __builtin_nontemporal_load(&maskw4[tid]);
        mb[0] = mvec.x; mb[1] = mvec.y; mb[2] = mvec.z; mb[3] = mvec.w;
    }

    // ---- compute 4 elements -> 4 output float4s ---------------------------
    f32x4 o0, o1, o2, o3;
    float e_[4] = {ev.x, ev.y, ev.z, ev.w};
    float w_[4] = {wv.x, wv.y, wv.z, wv.w};
    float o0_[4], o1_[4], o2_[4], o3_[4];
#pragma unroll
    for (int k = 0; k < 4; ++k) {
        int wi = (int)w_[k];               // exact: integers in [-32767, 32767]
        int p  = wi > 0 ?  wi : 0;
        int n  = wi > 0 ?  0  : -wi;
        int cp = (p >> shift) & 3;
        int cn = (n >> shift) & 3;

        float Gp = sel4(m4[k], cp) + e_[k] * sel4(s4[k], cp);
        float Gn = sel4(m4[k], cn) + e_[k] * sel4(s4[k], cn);
        bool  am = (mb[k] != 0u);

        o0_[k] = am ? Gp : 0.0f;
        o1_[k] = am ? Gn : 0.0f;
        o2_[k] = am ? 0.0f : Gp;
        o3_[k] = am ? 0.0f : Gn;
    }
    o0 = (f32x4){o0_[0], o0_[1], o0_[2], o0_[3]};
    o1 = (f32x4){o1_[0], o1_[1], o1_[2], o1_[3]};
    o2 = (f32x4){o2_[0], o2_[1], o2_[2], o2_[3]};
    o3 = (f32x4){o3_[0], o3_[1], o3_[2], o3_[3]};

    // ---- 4x 16B nontemporal stores ---------------------------------------
    __builtin_nontemporal_store(o0, &out4[tid]);
    __builtin_nontemporal_store(o1, &out4[(NELEM >> 2) + tid]);
    __builtin_nontemporal_store(o2, &out4[(NELEM >> 1) + tid]);
    __builtin_nontemporal_store(o3, &out4[3 * (NELEM >> 2) + tid]);
}

extern "C" void kernel_launch(void* const* d_in, const int* in_sizes, int n_in,
                              void* d_out, int out_size, void* d_ws, size_t ws_size,
                              hipStream_t stream) {
    const f32x4* input4 = (const f32x4*)d_in[0];
    const f32x4* meanG  = (const f32x4*)d_in[1];
    const f32x4* sigG   = (const f32x4*)d_in[2];
    const f32x4* eps4   = (const f32x4*)d_in[3];
    const void*  mask   = d_in[4];

    int threads = 256;
    int blocks  = NTHREADS_TOTAL / threads;   // 8192
    w2g_main_kernel<<<blocks, threads, 0, stream>>>(
        input4, meanG, sigG, eps4,
        (const unsigned int*)mask, (const u32x4*)mask,
        (f32x4*)d_out);
}

// Round 12
// 347.425 us; speedup vs baseline: 1.0293x; 1.0293x over previous
//
#include <hip/hip_runtime.h>

// Problem geometry: NEW_SHAPE = (16,16,512,64) flat-indexed as
//   idx = rc*32768 + i*64 + j   with rc = col*16+row, i in [0,512), j in [0,64)
//   weight element: (rc, i>>3, j); slice s = i&7 (MSB-first => shift = 14 - 2*s)
// 4 elements/thread at stride QUARTER: every wave instruction lane-contiguous
// (R6 winning pattern) + explicit load-all phase into named registers (MLP).
#define NELEM   (16 * 16 * 512 * 64)   // 8,388,608
#define QUARTER (NELEM / 4)            // 2,097,152 (bit 21 up => rc += 64/chunk)

typedef float f32x4 __attribute__((ext_vector_type(4)));

// branchless select of one lane of an f32x4 by code c in {0,1,2,3}
__device__ __forceinline__ float sel4(f32x4 v, int c) {
    return (c & 1) ? ((c & 2) ? v.w : v.y)
                   : ((c & 2) ? v.z : v.x);
}

__device__ __forceinline__ void compute_store(
    f32x4 m4, f32x4 s4, float e, float w, unsigned int mk,
    int shift, int idx, float* __restrict__ out)
{
    int wi = (int)w;                   // exact: integers in [-32767, 32767]
    int p  = wi > 0 ?  wi : 0;
    int n  = wi > 0 ?  0  : -wi;
    int cp = (p >> shift) & 3;
    int cn = (n >> shift) & 3;

    float Gp = sel4(m4, cp) + e * sel4(s4, cp);
    float Gn = sel4(m4, cn) + e * sel4(s4, cn);
    bool  am = (mk != 0u);

    __builtin_nontemporal_store(am ? Gp : 0.0f, &out[idx]);
    __builtin_nontemporal_store(am ? Gn : 0.0f, &out[NELEM + idx]);
    __builtin_nontemporal_store(am ? 0.0f : Gp, &out[2 * NELEM + idx]);
    __builtin_nontemporal_store(am ? 0.0f : Gn, &out[3 * NELEM + idx]);
}

__global__ __launch_bounds__(256) void w2g_main_kernel(
    const float*  __restrict__ input,     // (16,16,64,64) fp32, 4 MB (L2/L3-resident)
    const f32x4*  __restrict__ meanG,     // (NELEM,4) fp32, single-use stream
    const f32x4*  __restrict__ sigG,      // (NELEM,4) fp32, single-use stream
    const float*  __restrict__ eps,       // (NELEM) fp32, single-use stream
    const unsigned char* __restrict__ mask8,
    const unsigned int*  __restrict__ maskw,
    float* __restrict__ out)              // 4*NELEM: [Gp*am][Gn*am][Gp*!am][Gn*!am]
{
    int tid = blockIdx.x * blockDim.x + threadIdx.x;   // [0, QUARTER)

    // ---- inline mask-dtype detection (wave-uniform, first 64 words) -------
    // byte-bool mask -> some word > 1 and none == 0x3F800000; int32/float32
    // masks both reduce to (word != 0), so only byte-vs-word matters.
    unsigned int probe = maskw[threadIdx.x & 63];
    bool isF = (probe == 0x3F800000u);
    bool isB = (probe > 1u) && !isF;
    unsigned long long anyF = __ballot(isF);
    unsigned long long anyB = __ballot(isB);
    bool byteMode = (anyF == 0ull) && (anyB != 0ull);

    // ---- index decomposition shared by all 4 strided elements -------------
    // k*QUARTER only touches bits >= 21, so j, i, shift are k-invariant.
    int j     = tid & 63;
    int i     = (tid >> 6) & 511;
    int rc0   = tid >> 15;                 // [0,64)
    int shift = 14 - 2 * (i & 7);          // MSB-first 2-bit slice
    int ibase = ((i >> 3) << 6) | j;       // weight offset within one rc plane

    int idx0 = tid;
    int idx1 = tid + QUARTER;
    int idx2 = tid + 2 * QUARTER;
    int idx3 = tid + 3 * QUARTER;

    // ---- phase 1: issue ALL loads into distinct named registers -----------
    f32x4 m0 = __builtin_nontemporal_load(&meanG[idx0]);
    f32x4 m1 = __builtin_nontemporal_load(&meanG[idx1]);
    f32x4 m2 = __builtin_nontemporal_load(&meanG[idx2]);
    f32x4 m3 = __builtin_nontemporal_load(&meanG[idx3]);
    f32x4 s0 = __builtin_nontemporal_load(&sigG[idx0]);
    f32x4 s1 = __builtin_nontemporal_load(&sigG[idx1]);
    f32x4 s2 = __builtin_nontemporal_load(&sigG[idx2]);
    f32x4 s3 = __builtin_nontemporal_load(&sigG[idx3]);
    float e0 = __builtin_nontemporal_load(&eps[idx0]);
    float e1 = __builtin_nontemporal_load(&eps[idx1]);
    float e2 = __builtin_nontemporal_load(&eps[idx2]);
    float e3 = __builtin_nontemporal_load(&eps[idx3]);
    float w0 = input[((rc0      ) << 12) | ibase];     // L2/L3-resident
    float w1 = input[((rc0 +  64) << 12) | ibase];
    float w2 = input[((rc0 + 128) << 12) | ibase];
    float w3 = input[((rc0 + 192) << 12) | ibase];

    unsigned int k0, k1, k2, k3;
    if (byteMode) {
        k0 = mask8[idx0]; k1 = mask8[idx1]; k2 = mask8[idx2]; k3 = mask8[idx3];
    } else {
        k0 = maskw[idx0]; k1 = maskw[idx1]; k2 = maskw[idx2]; k3 = maskw[idx3];
    }

    // ---- phase 2: compute + store -----------------------------------------
    compute_store(m0, s0, e0, w0, k0, shift, idx0, out);
    compute_store(m1, s1, e1, w1, k1, shift, idx1, out);
    compute_store(m2, s2, e2, w2, k2, shift, idx2, out);
    compute_store(m3, s3, e3, w3, k3, shift, idx3, out);
}

extern "C" void kernel_launch(void* const* d_in, const int* in_sizes, int n_in,
                              void* d_out, int out_size, void* d_ws, size_t ws_size,
                              hipStream_t stream) {
    const float*  input = (const float*) d_in[0];
    const f32x4*  meanG = (const f32x4*) d_in[1];
    const f32x4*  sigG  = (const f32x4*) d_in[2];
    const float*  eps   = (const float*) d_in[3];
    const void*   mask  = d_in[4];

    int threads = 256;
    int blocks  = QUARTER / threads;       // 8192
    w2g_main_kernel<<<blocks, threads, 0, stream>>>(
        input, meanG, sigG, eps,
        (const unsigned char*)mask, (const unsigned int*)mask,
        (float*)d_out);
}